// Round 8
// baseline (227.148 us; speedup 1.0000x reference)
//
#include <hip/hip_runtime.h>
#include <math.h>

#define IN_DIM 128
#define HID 64
#define HEADS 4
#define NEG_SLOPE 0.2f
#define LN_EPS 1e-5f
#define APAD 328            // Atile row pitch in bf16 elems
#define EC 176              // max edges per 16-dst block for fast path
#define KMAXP 192           // EC+16 self edges, = max K (multiple of 32)
#define PADB 72             // B LDS row pitch (bf16 elems), 16B-aligned rows
#define PADP 200            // P LDS row pitch (bf16 elems), 16B-aligned rows

typedef short bf16x8 __attribute__((ext_vector_type(8)));
typedef float f32x4  __attribute__((ext_vector_type(4)));
typedef unsigned short u16x4 __attribute__((ext_vector_type(4)));
typedef unsigned long long ull;

// ---------- bf16 helpers ----------
__device__ inline unsigned short f2bf(float f) {
    unsigned u = __float_as_uint(f);
    u += 0x7fffu + ((u >> 16) & 1u);     // round-to-nearest-even
    return (unsigned short)(u >> 16);
}
__device__ inline float bf2f(unsigned short s) {
    return __uint_as_float(((unsigned)s) << 16);
}
__device__ inline float leaky(float v) { return v > 0.0f ? v : NEG_SLOPE * v; }

// ---------- fused: weight pre-pack + att fold + flag + A-zero + dst histogram ----------
__global__ __launch_bounds__(256) void k_init(const void* ei, int E, int n,
                           int* flag, int* hist, ull* A,
                           const float* __restrict__ Wg, const float* __restrict__ Wp,
                           const float* __restrict__ Wgcn,
                           const float* __restrict__ att_s, const float* __restrict__ att_d,
                           unsigned short* __restrict__ Wt_post,
                           unsigned short* __restrict__ Wt_xw,
                           float* __restrict__ w_s, float* __restrict__ w_d) {
    int t = threadIdx.x;
    int role = blockIdx.x;
    if (role < 14) {
        int p = role * 256 + t;
        if (p < 2560) {
            int c = p & 63, kg = p >> 6;
            bf16x8 v;
#pragma unroll
            for (int j = 0; j < 8; j++) {
                int k = kg * 8 + j;
                float f;
                if (k < 256) f = 0.25f * Wg[(size_t)(k & 63) * 256 + (k >> 6) * 64 + c];
                else         f = Wp[(size_t)(k - 256) * 64 + c];
                v[j] = (short)f2bf(f);
            }
            *(bf16x8*)(&Wt_post[(size_t)p * 8]) = v;
        } else if (p < 2560 + 1024) {
            int q = p - 2560;
            int c = q & 63, kg = q >> 6;
            bf16x8 v;
#pragma unroll
            for (int j = 0; j < 8; j++)
                v[j] = (short)f2bf(Wgcn[(size_t)(kg * 8 + j) * 64 + c]);
            *(bf16x8*)(&Wt_xw[(size_t)q * 8]) = v;
        }
        return;
    }
    if (role == 14) {
        A[t] = 0ULL;                       // lookback state (nch <= 256)
        __shared__ int s_bad;
        if (t == 0) s_bad = 0;
        __syncthreads();
        int lim = E < 512 ? E : 512;
        int bad = 0;
        for (int k = t; k < lim; k += 256)
            if (((const ull*)ei)[k] >= (ull)n) bad = 1;
        if (bad) s_bad = 1;                // benign race
        __syncthreads();
        if (t == 0) *flag = s_bad ? 0 : 1; // 1 = genuine int64
        int h = t >> 6, k = t & 63;
        float ss = 0.0f, sd = 0.0f;
        for (int c = 0; c < HID; c++) {
            float w = Wg[(size_t)k * (HEADS * HID) + h * HID + c];
            ss += w * att_s[h * HID + c];
            sd += w * att_d[h * HID + c];
        }
        w_s[h * HID + k] = ss;
        w_d[h * HID + k] = sd;
        return;
    }
    __shared__ int s_bad2;
    if (t == 0) s_bad2 = 0;
    __syncthreads();
    int lim = E < 512 ? E : 512;
    int bad = 0;
    for (int k = t; k < lim; k += 256)
        if (((const ull*)ei)[k] >= (ull)n) bad = 1;
    if (bad) s_bad2 = 1;
    __syncthreads();
    int is64 = s_bad2 ? 0 : 1;
    int hb = role - 15;
    int nhb = gridDim.x - 15;
    for (int i = hb * 256 + t; i < E; i += nhb * 256) {
        int d;
        if (is64) d = (int)((const long long*)ei)[E + i];
        else      d = ((const int*)ei)[E + i];
        atomicAdd(&hist[d], 1);
    }
}

// ---------- single-kernel scan: per-chunk scan + wave-parallel decoupled lookback ----------
__global__ __launch_bounds__(256) void k_scan_lb(const int* __restrict__ hist,
                                                 ull* __restrict__ A,
                                                 int* __restrict__ row_ptr,
                                                 int* __restrict__ cursor,
                                                 float* __restrict__ dinv, int n) {
    __shared__ int s[256];
    __shared__ int sbase;
    int t = threadIdx.x, c = blockIdx.x;
    int w = t >> 6, lane = t & 63;
    int i = c * 256 + t;
    int v = (i < n) ? hist[i] : 0;
    s[t] = v;
    __syncthreads();
    for (int off = 1; off < 256; off <<= 1) {
        int xv = (t >= off) ? s[t - off] : 0;
        __syncthreads();
        s[t] += xv;
        __syncthreads();
    }
    int incl = s[t];
    int S = s[255];
    if (t == 0) {
        if (c == 0) { sbase = 0; atomicExch(&A[0], (2ULL << 32) | (unsigned)S); }
        else          atomicExch(&A[c], (1ULL << 32) | (unsigned)S);
    }
    if (c > 0 && w == 0) {
        long long run = 0;
        int p = c - 1;
        for (;;) {
            int idx = p - lane;
            unsigned st, val;
            if (idx >= 0) {
                ull v2 = atomicAdd(&A[idx], 0ULL);
                st = (unsigned)(v2 >> 32); val = (unsigned)v2;
            } else { st = 2u; val = 0u; }
            ull pm = __ballot(st == 2);
            ull zm = __ballot(st == 0);
            int firstP = pm ? (__ffsll((long long)pm) - 1) : 64;
            int firstZ = zm ? (__ffsll((long long)zm) - 1) : 64;
            if (firstZ < firstP) { __builtin_amdgcn_s_sleep(1); continue; }
            unsigned contrib = (lane <= firstP) ? val : 0u;
#pragma unroll
            for (int o = 1; o <= 32; o <<= 1) contrib += __shfl_xor(contrib, o, 64);
            run += contrib;
            if (firstP < 64) break;
            p -= 64;
        }
        if (lane == 0) {
            sbase = (int)run;
            atomicExch(&A[c], (2ULL << 32) | (unsigned)(run + (unsigned)S));
        }
    }
    __syncthreads();
    if (i < n) {
        int excl = sbase + incl - v;
        row_ptr[i] = excl;
        cursor[i] = excl;
        dinv[i] = rsqrtf((float)(v + 1));   // +1 self-loop
    }
}

// ---------- fused: CSR scatter (from raw edge_index) + MFMA x@W_gcn ----------
__global__ __launch_bounds__(256) void k_scatter_xw(const void* ei, int E,
                                                    const int* __restrict__ flag,
                                                    int* __restrict__ cursor,
                                                    int* __restrict__ col,
                                                    const float* __restrict__ x,
                                                    const unsigned short* __restrict__ Wt_g,
                                                    const float* __restrict__ dinv,
                                                    unsigned short* __restrict__ xws, int n) {
    __shared__ unsigned short Wt[16 * 64 * 8];   // 16 KB (used by xw half only)
    int nsb = (E + 255) >> 8;
    if ((int)blockIdx.x < nsb) {
        int i = blockIdx.x * 256 + threadIdx.x;
        if (i >= E) return;
        int is64 = *flag;
        int s, d;
        if (is64) { s = (int)((const long long*)ei)[i]; d = (int)((const long long*)ei)[E + i]; }
        else      { s = ((const int*)ei)[i];            d = ((const int*)ei)[E + i]; }
        int pos = atomicAdd(&cursor[d], 1);
        col[pos] = s;
    } else {
        int bx = blockIdx.x - nsb;
        int t = threadIdx.x;
        for (int idx = t; idx < 1024; idx += 256)
            *(bf16x8*)(&Wt[idx * 8]) = *(const bf16x8*)(&Wt_g[(size_t)idx * 8]);
        __syncthreads();
        int lane = t & 63;
        int li = lane & 15, quad = lane >> 4;
        int w = t >> 6;
        int r0 = bx * 64 + w * 16;
        int rload = r0 + li; if (rload > n - 1) rload = n - 1;
        f32x4 acc[4];
#pragma unroll
        for (int i = 0; i < 4; i++) acc[i] = (f32x4){0.f, 0.f, 0.f, 0.f};
        const float* xp = x + (size_t)rload * IN_DIM + quad * 8;
#pragma unroll
        for (int ks = 0; ks < 4; ks++) {
            float4 p0 = *(const float4*)(xp + ks * 32);
            float4 p1 = *(const float4*)(xp + ks * 32 + 4);
            bf16x8 a;
            a[0] = (short)f2bf(p0.x); a[1] = (short)f2bf(p0.y);
            a[2] = (short)f2bf(p0.z); a[3] = (short)f2bf(p0.w);
            a[4] = (short)f2bf(p1.x); a[5] = (short)f2bf(p1.y);
            a[6] = (short)f2bf(p1.z); a[7] = (short)f2bf(p1.w);
            int kg = ks * 4 + quad;
#pragma unroll
            for (int tt = 0; tt < 4; tt++) {
                bf16x8 bfr = *(const bf16x8*)(&Wt[((kg * 64) + tt * 16 + li) * 8]);
                acc[tt] = __builtin_amdgcn_mfma_f32_16x16x32_bf16(a, bfr, acc[tt], 0, 0, 0);
            }
        }
#pragma unroll
        for (int reg = 0; reg < 4; reg++) {
            int r = r0 + quad * 4 + reg;
            if (r >= n) continue;
            float dv = dinv[r];
#pragma unroll
            for (int tt = 0; tt < 4; tt++)
                xws[(size_t)r * HID + tt * 16 + li] = f2bf(acc[tt][reg] * dv);
        }
    }
}

// ---------- GCN gather: broadcast col loads, 4 gathers in flight ----------
__global__ __launch_bounds__(256) void k_gcn(const int* __restrict__ col,
                                             const int* __restrict__ row_ptr,
                                             const int* __restrict__ hist,
                                             const float* __restrict__ dinv,
                                             const unsigned short* __restrict__ xws,
                                             const float* __restrict__ b,
                                             const float* __restrict__ w_s,
                                             const float* __restrict__ w_d,
                                             unsigned short* __restrict__ h1b,
                                             float4* __restrict__ a_s,
                                             float4* __restrict__ a_d, int n) {
    int t = threadIdx.x;
    int w = t >> 6, lane = t & 63, q = lane >> 4, li = lane & 15;
    int d = blockIdx.x * 4 + w;
    if (d >= n) return;
    int start = row_ptr[d], cnt = hist[d];
    float a0, a1, a2, a3;
    {
        u16x4 sv = *(const u16x4*)(xws + (size_t)d * HID + li * 4);
        float z = (q == 0) ? 1.0f : 0.0f;
        a0 = z * bf2f(sv[0]); a1 = z * bf2f(sv[1]);
        a2 = z * bf2f(sv[2]); a3 = z * bf2f(sv[3]);
    }
    for (int kb = q; kb < cnt; kb += 16) {
        int k1 = kb + 4, k2 = kb + 8, k3 = kb + 12;
        int i1 = k1 < cnt ? k1 : kb;
        int i2 = k2 < cnt ? k2 : kb;
        int i3 = k3 < cnt ? k3 : kb;
        int s0 = col[start + kb];
        int s1 = col[start + i1];
        int s2 = col[start + i2];
        int s3 = col[start + i3];
        u16x4 v0 = *(const u16x4*)(xws + (size_t)s0 * HID + li * 4);
        u16x4 v1 = *(const u16x4*)(xws + (size_t)s1 * HID + li * 4);
        u16x4 v2 = *(const u16x4*)(xws + (size_t)s2 * HID + li * 4);
        u16x4 v3 = *(const u16x4*)(xws + (size_t)s3 * HID + li * 4);
        float g1 = (k1 < cnt) ? 1.0f : 0.0f;
        float g2 = (k2 < cnt) ? 1.0f : 0.0f;
        float g3 = (k3 < cnt) ? 1.0f : 0.0f;
        a0 += (bf2f(v0[0]) + g1 * bf2f(v1[0])) + (g2 * bf2f(v2[0]) + g3 * bf2f(v3[0]));
        a1 += (bf2f(v0[1]) + g1 * bf2f(v1[1])) + (g2 * bf2f(v2[1]) + g3 * bf2f(v3[1]));
        a2 += (bf2f(v0[2]) + g1 * bf2f(v1[2])) + (g2 * bf2f(v2[2]) + g3 * bf2f(v3[2]));
        a3 += (bf2f(v0[3]) + g1 * bf2f(v1[3])) + (g2 * bf2f(v2[3]) + g3 * bf2f(v3[3]));
    }
    a0 += __shfl_xor(a0, 16, 64); a1 += __shfl_xor(a1, 16, 64);
    a2 += __shfl_xor(a2, 16, 64); a3 += __shfl_xor(a3, 16, 64);
    a0 += __shfl_xor(a0, 32, 64); a1 += __shfl_xor(a1, 32, 64);
    a2 += __shfl_xor(a2, 32, 64); a3 += __shfl_xor(a3, 32, 64);
    float dv = dinv[d];
    float4 bv = *(const float4*)(b + li * 4);
    float h0 = fmaxf(a0 * dv + bv.x, 0.0f);
    float h1 = fmaxf(a1 * dv + bv.y, 0.0f);
    float h2 = fmaxf(a2 * dv + bv.z, 0.0f);
    float h3 = fmaxf(a3 * dv + bv.w, 0.0f);
    if (q == 0) {
        u16x4 o;
        o[0] = f2bf(h0); o[1] = f2bf(h1); o[2] = f2bf(h2); o[3] = f2bf(h3);
        *(u16x4*)(h1b + (size_t)d * HID + li * 4) = o;
    }
    float4 u  = *(const float4*)(w_s + q * 64 + li * 4);
    float vs = h0 * u.x + h1 * u.y + h2 * u.z + h3 * u.w;
    float4 u2 = *(const float4*)(w_d + q * 64 + li * 4);
    float vd = h0 * u2.x + h1 * u2.y + h2 * u2.z + h3 * u2.w;
#pragma unroll
    for (int o = 1; o <= 8; o <<= 1) {
        vs += __shfl_xor(vs, o, 64);
        vd += __shfl_xor(vd, o, 64);
    }
    float vs1 = __shfl(vs, 16, 64), vs2 = __shfl(vs, 32, 64), vs3 = __shfl(vs, 48, 64);
    float vd1 = __shfl(vd, 16, 64), vd2 = __shfl(vd, 32, 64), vd3 = __shfl(vd, 48, 64);
    if (lane == 0) {
        a_s[d] = make_float4(vs, vs1, vs2, vs3);
        a_d[d] = make_float4(vd, vd1, vd2, vd3);
    }
}

// ---------- FUSED attention (MFMA sparse-agg) + post-GEMM + residual/LN ----------
// Fast path: W1 edge-parallel weights->P[64][K] (LDS), W2 (edge,part)-parallel h1b
// gather -> B[K][64] (LDS, col-swizzled), M: dense MFMA P*B (2x2 tiles/wave),
// normalize by LDS-atomic l -> Atile. Fallback (totc>EC): R7 per-dst serial loop.
// Phase B/C: verified post-GEMM + LayerNorm, unchanged.
__global__ __launch_bounds__(256) void k_attn_post(
        const int* __restrict__ col, const int* __restrict__ row_ptr,
        const int* __restrict__ hist,
        const float4* __restrict__ a_s, const float4* __restrict__ a_d,
        const unsigned short* __restrict__ h1b,
        const unsigned short* __restrict__ Wt_g,
        const float* __restrict__ bp, const float* __restrict__ bg,
        const float* __restrict__ gamma, const float* __restrict__ beta,
        float* __restrict__ out, int n) {
    __shared__ __align__(16) unsigned short P[64 * PADP];     // 25.6 KB
    __shared__ __align__(16) unsigned short Bls[KMAXP * PADB]; // 27 KB
    __shared__ __align__(16) unsigned short Atile[16 * APAD];  // 10.25 KB
    __shared__ float l_sh[64];
    __shared__ int sls[KMAXP];
    __shared__ int sb[17];
    __shared__ float4 sad[16];
    float* hbuf = (float*)P;   // alias: P dead before phase B writes hbuf

    int t = threadIdx.x;
    int w = t >> 6, lane = t & 63, q = lane >> 4, li = lane & 15;
    int rowbase = blockIdx.x * 16;

    if (t < 17) {
        int d2 = rowbase + t;
        int dd = d2 < n ? d2 : n - 1;
        sb[t] = row_ptr[dd] + ((d2 < n) ? 0 : hist[dd]);
    }
    if (t < 16) {
        int d = rowbase + t;
        sad[t] = (d < n) ? a_d[d] : make_float4(0.f, 0.f, 0.f, 0.f);
    }
    if (t < 64) l_sh[t] = 0.0f;
    __syncthreads();
    int start0 = sb[0];
    int totc = sb[16] - start0;
    int K_used = totc + 16;
    int K_pad = (K_used + 31) & ~31;
    bool fast = (totc <= EC);

    if (fast) {
        // zero P fully (garbage cols contribute 0 to MFMA)
        bf16x8 z8 = {0, 0, 0, 0, 0, 0, 0, 0};
        for (int i = t; i < 64 * PADP / 8; i += 256) ((bf16x8*)P)[i] = z8;
        // zero B pad rows [K_used, K_pad)
        for (int i = K_used * (PADB / 8) + t; i < K_pad * (PADB / 8); i += 256)
            ((bf16x8*)Bls)[i] = z8;
        // W1: one thread per edge
        if (t < totc) {
            int e = t;
            int s = col[start0 + e];
            int j = 0;
#pragma unroll
            for (int jj = 1; jj < 16; jj++) j += (e >= (sb[jj] - start0)) ? 1 : 0;
            float4 as = a_s[s], ad = sad[j];
            unsigned short q0 = f2bf(__expf(leaky(as.x + ad.x)));
            unsigned short q1 = f2bf(__expf(leaky(as.y + ad.y)));
            unsigned short q2 = f2bf(__expf(leaky(as.z + ad.z)));
            unsigned short q3 = f2bf(__expf(leaky(as.w + ad.w)));
            P[(j * 4 + 0) * PADP + e] = q0;
            P[(j * 4 + 1) * PADP + e] = q1;
            P[(j * 4 + 2) * PADP + e] = q2;
            P[(j * 4 + 3) * PADP + e] = q3;
            sls[e] = s;
            atomicAdd(&l_sh[j * 4 + 0], bf2f(q0));
            atomicAdd(&l_sh[j * 4 + 1], bf2f(q1));
            atomicAdd(&l_sh[j * 4 + 2], bf2f(q2));
            atomicAdd(&l_sh[j * 4 + 3], bf2f(q3));
        }
        // self edges (slots totc..totc+15)
        if (t < 16) {
            int d = rowbase + t;
            if (d < n) {
                float4 as = a_s[d], ad = sad[t];
                unsigned short q0 = f2bf(__expf(leaky(as.x + ad.x)));
                unsigned short q1 = f2bf(__expf(leaky(as.y + ad.y)));
                unsigned short q2 = f2bf(__expf(leaky(as.z + ad.z)));
                unsigned short q3 = f2bf(__expf(leaky(as.w + ad.w)));
                int e = totc + t;
                P[(t * 4 + 0) * PADP + e] = q0;
                P[(t * 4 + 1) * PADP + e] = q1;
                P[(t * 4 + 2) * PADP + e] = q2;
                P[(t * 4 + 3) * PADP + e] = q3;
                sls[e] = d;
                atomicAdd(&l_sh[t * 4 + 0], bf2f(q0));
                atomicAdd(&l_sh[t * 4 + 1], bf2f(q1));
                atomicAdd(&l_sh[t * 4 + 2], bf2f(q2));
                atomicAdd(&l_sh[t * 4 + 3], bf2f(q3));
            } else {
                sls[totc + t] = 0;
            }
        }
    }
    __syncthreads();

    if (fast) {
        // W2: (edge, 16B-part)-parallel gather of h1b rows into B (col-swizzled)
        for (int idx = t; idx < K_used * 8; idx += 256) {
            int e = idx >> 3, p = idx & 7;
            int s = sls[e];
            bf16x8 v = *(const bf16x8*)(h1b + (size_t)s * HID + p * 8);
            int cb = p ^ ((e >> 3) & 3);
            *(bf16x8*)(&Bls[e * PADB + cb * 8]) = v;
        }
        // Atile h1 cols 256..319 (self rows, direct from global)
        if (t < 128) {
            int dl = t >> 3, p = t & 7;
            int d = rowbase + dl;
            bf16x8 v = {0, 0, 0, 0, 0, 0, 0, 0};
            if (d < n) v = *(const bf16x8*)(h1b + (size_t)d * HID + p * 8);
            *(bf16x8*)(&Atile[dl * APAD + 256 + p * 8]) = v;
        }
    }
    __syncthreads();

    if (fast) {
        // M: OUT[64 rows=(d,h)][64 ch] = P * B, 2x2 16x16 tiles per wave
        int rt0 = (w >> 1) * 2, ct0 = (w & 1) * 2;
        f32x4 acc[2][2];
#pragma unroll
        for (int i = 0; i < 2; i++)
#pragma unroll
            for (int jj = 0; jj < 2; jj++) acc[i][jj] = (f32x4){0.f, 0.f, 0.f, 0.f};
        int kmax = K_pad >> 5;
        for (int ks = 0; ks < kmax; ks++) {
            bf16x8 af0 = *(const bf16x8*)(&P[((rt0 + 0) * 16 + li) * PADP + ks * 32 + q * 8]);
            bf16x8 af1 = *(const bf16x8*)(&P[((rt0 + 1) * 16 + li) * PADP + ks * 32 + q * 8]);
            int kbase = ks * 32 + q * 8;
            bf16x8 bf[2];
#pragma unroll
            for (int jj = 0; jj < 2; jj++) {
                int c = (ct0 + jj) * 16 + li;
                int ccol = (((c >> 3) ^ q) << 3) | (c & 7);
                bf16x8 bb;
#pragma unroll
                for (int jx = 0; jx < 8; jx++)
                    bb[jx] = (short)Bls[(kbase + jx) * PADB + ccol];
                bf[jj] = bb;
            }
            acc[0][0] = __builtin_amdgcn_mfma_f32_16x16x32_bf16(af0, bf[0], acc[0][0], 0, 0, 0);
            acc[0][1] = __builtin_amdgcn_mfma_f32_16x16x32_bf16(af0, bf[1], acc[0][1], 0, 0, 0);
            acc[1][0] = __builtin_amdgcn_mfma_f32_16x16x32_bf16(af1, bf[0], acc[1][0], 0, 0, 0);
            acc[1][1] = __builtin_amdgcn_mfma_f32_16x16x32_bf16(af1, bf[1], acc[1][1], 0, 0, 0);
        }
        // normalize + write Atile cols 0..255
#pragma unroll
        for (int i = 0; i < 2; i++) {
            float invl[4];
#pragma unroll
            for (int reg = 0; reg < 4; reg++) {
                int r = (rt0 + i) * 16 + q * 4 + reg;
                float lv = l_sh[r];
                invl[reg] = (lv > 0.0f) ? 1.0f / lv : 0.0f;
            }
#pragma unroll
            for (int jj = 0; jj < 2; jj++) {
                int c = (ct0 + jj) * 16 + li;
#pragma unroll
                for (int reg = 0; reg < 4; reg++) {
                    int r = (rt0 + i) * 16 + q * 4 + reg;
                    int dl = r >> 2, h = r & 3;
                    Atile[dl * APAD + h * 64 + c] = f2bf(acc[i][jj][reg] * invl[reg]);
                }
            }
        }
    } else {
        // -------- fallback: R7 per-dst serial path (verified) --------
        for (int j = 0; j < 4; j++) {
            int r = w * 4 + j;
            int d = rowbase + r;
            if (d >= n) {
                for (int c = lane; c < 320; c += 64) Atile[r * APAD + c] = 0;
                continue;
            }
            int start = row_ptr[d], cnt = hist[d];
            float4 ad = a_d[d];
            float4 asd = a_s[d];
            u16x4 sv = *(const u16x4*)(h1b + (size_t)d * HID + li * 4);
            float e0 = __expf(leaky(asd.x + ad.x));
            float e1 = __expf(leaky(asd.y + ad.y));
            float e2 = __expf(leaky(asd.z + ad.z));
            float e3 = __expf(leaky(asd.w + ad.w));
            float z = (q == 0) ? 1.0f : 0.0f;
            float f0 = bf2f(sv[0]), f1 = bf2f(sv[1]), f2 = bf2f(sv[2]), f3 = bf2f(sv[3]);
            f32x4 A0 = {z * e0 * f0, z * e0 * f1, z * e0 * f2, z * e0 * f3};
            f32x4 A1 = {z * e1 * f0, z * e1 * f1, z * e1 * f2, z * e1 * f3};
            f32x4 A2 = {z * e2 * f0, z * e2 * f1, z * e2 * f2, z * e2 * f3};
            f32x4 A3 = {z * e3 * f0, z * e3 * f1, z * e3 * f2, z * e3 * f3};
            float l0 = z * e0, l1 = z * e1, l2 = z * e2, l3 = z * e3;
            for (int kb = q; kb < cnt; kb += 8) {
                int k1 = kb + 4;
                int i1 = k1 < cnt ? k1 : kb;
                int s0 = col[start + kb];
                int s1 = col[start + i1];
                float4 as0 = a_s[s0];
                float4 as1 = a_s[s1];
                u16x4 hv0 = *(const u16x4*)(h1b + (size_t)s0 * HID + li * 4);
                u16x4 hv1 = *(const u16x4*)(h1b + (size_t)s1 * HID + li * 4);
                float g1 = (k1 < cnt) ? 1.0f : 0.0f;
                float w00 = __expf(leaky(as0.x + ad.x));
                float w01 = __expf(leaky(as0.y + ad.y));
                float w02 = __expf(leaky(as0.z + ad.z));
                float w03 = __expf(leaky(as0.w + ad.w));
                float w10 = g1 * __expf(leaky(as1.x + ad.x));
                float w11 = g1 * __expf(leaky(as1.y + ad.y));
                float w12 = g1 * __expf(leaky(as1.z + ad.z));
                float w13 = g1 * __expf(leaky(as1.w + ad.w));
                float g00 = bf2f(hv0[0]), g01 = bf2f(hv0[1]);
                float g02 = bf2f(hv0[2]), g03 = bf2f(hv0[3]);
                float g10 = bf2f(hv1[0]), g11 = bf2f(hv1[1]);
                float g12 = bf2f(hv1[2]), g13 = bf2f(hv1[3]);
                A0[0] += w00 * g00 + w10 * g10; A0[1] += w00 * g01 + w10 * g11;
                A0[2] += w00 * g02 + w10 * g12; A0[3] += w00 * g03 + w10 * g13;
                A1[0] += w01 * g00 + w11 * g10; A1[1] += w01 * g01 + w11 * g11;
                A1[2] += w01 * g02 + w11 * g12; A1[3] += w01 * g03 + w11 * g13;
                A2[0] += w02 * g00 + w12 * g10; A2[1] += w02 * g01 + w12 * g11;
                A2[2] += w02 * g02 + w12 * g12; A2[3] += w02 * g03 + w12 * g13;
                A3[0] += w03 * g00 + w13 * g10; A3[1] += w03 * g01 + w13 * g11;
                A3[2] += w03 * g02 + w13 * g12; A3[3] += w03 * g03 + w13 * g13;
                l0 += w00 + w10; l1 += w01 + w11;
                l2 += w02 + w12; l3 += w03 + w13;
            }
#pragma unroll
            for (int c4 = 0; c4 < 4; c4++) {
                A0[c4] += __shfl_xor(A0[c4], 16, 64);
                A1[c4] += __shfl_xor(A1[c4], 16, 64);
                A2[c4] += __shfl_xor(A2[c4], 16, 64);
                A3[c4] += __shfl_xor(A3[c4], 16, 64);
            }
            l0 += __shfl_xor(l0, 16, 64); l1 += __shfl_xor(l1, 16, 64);
            l2 += __shfl_xor(l2, 16, 64); l3 += __shfl_xor(l3, 16, 64);
#pragma unroll
            for (int c4 = 0; c4 < 4; c4++) {
                A0[c4] += __shfl_xor(A0[c4], 32, 64);
                A1[c4] += __shfl_xor(A1[c4], 32, 64);
                A2[c4] += __shfl_xor(A2[c4], 32, 64);
                A3[c4] += __shfl_xor(A3[c4], 32, 64);
            }
            l0 += __shfl_xor(l0, 32, 64); l1 += __shfl_xor(l1, 32, 64);
            l2 += __shfl_xor(l2, 32, 64); l3 += __shfl_xor(l3, 32, 64);
            f32x4 Aq; float lq;
            if (q == 0)      { Aq = A0; lq = l0; }
            else if (q == 1) { Aq = A1; lq = l1; }
            else if (q == 2) { Aq = A2; lq = l2; }
            else             { Aq = A3; lq = l3; }
            float inv = 1.0f / lq;
            u16x4 o;
            o[0] = f2bf(Aq[0] * inv); o[1] = f2bf(Aq[1] * inv);
            o[2] = f2bf(Aq[2] * inv); o[3] = f2bf(Aq[3] * inv);
            *(u16x4*)(&Atile[r * APAD + q * 64 + li * 4]) = o;
            if (q == 0) *(u16x4*)(&Atile[r * APAD + 256 + li * 4]) = sv;
        }
    }
    __syncthreads();

    // ---- Phase B: MFMA post-GEMM. Wave w -> out cols w*16..+15, rows 0..15 ----
    f32x4 acc_a = {0.f, 0.f, 0.f, 0.f}, acc_h = {0.f, 0.f, 0.f, 0.f};
#pragma unroll
    for (int ks = 0; ks < 10; ks++) {
        int kg = ks * 4 + q;
        bf16x8 a = *(const bf16x8*)(&Atile[li * APAD + ks * 32 + q * 8]);
        bf16x8 bb = *(const bf16x8*)(&Wt_g[(size_t)(kg * 64 + w * 16 + li) * 8]);
        if (ks < 8) acc_a = __builtin_amdgcn_mfma_f32_16x16x32_bf16(a, bb, acc_a, 0, 0, 0);
        else        acc_h = __builtin_amdgcn_mfma_f32_16x16x32_bf16(a, bb, acc_h, 0, 0, 0);
    }
    int cc = w * 16 + li;
    float bgv = bg[cc], bpv = bp[cc];
#pragma unroll
    for (int reg = 0; reg < 4; reg++) {
        int r = q * 4 + reg;
        float h1c = bf2f(Atile[r * APAD + 256 + cc]);
        float h2v = fmaxf(acc_a[reg] + bgv, 0.0f);
        hbuf[r * 68 + cc] = h1c + h2v + acc_h[reg] + bpv;
    }
    __syncthreads();

    // ---- Phase C: LayerNorm (16 threads per row, 4 cols each) ----
    int row = t >> 4, lj = t & 15;
    f32x4 hv4 = *(const f32x4*)(&hbuf[row * 68 + lj * 4]);
    float s1 = (hv4[0] + hv4[1]) + (hv4[2] + hv4[3]);
    float s2 = (hv4[0] * hv4[0] + hv4[1] * hv4[1]) + (hv4[2] * hv4[2] + hv4[3] * hv4[3]);
#pragma unroll
    for (int o = 1; o <= 8; o <<= 1) {
        s1 += __shfl_xor(s1, o, 64);
        s2 += __shfl_xor(s2, o, 64);
    }
    float mu = s1 * (1.0f / 64.0f);
    float var = s2 * (1.0f / 64.0f) - mu * mu;
    float rs = rsqrtf(var + LN_EPS);
    int rg = rowbase + row;
    if (rg < n) {
        float4 g4 = *(const float4*)(gamma + lj * 4);
        float4 b4 = *(const float4*)(beta + lj * 4);
        float4 ov;
        ov.x = (hv4[0] - mu) * rs * g4.x + b4.x;
        ov.y = (hv4[1] - mu) * rs * g4.y + b4.y;
        ov.z = (hv4[2] - mu) * rs * g4.z + b4.z;
        ov.w = (hv4[3] - mu) * rs * g4.w + b4.w;
        *(float4*)(out + (size_t)rg * HID + lj * 4) = ov;
    }
}

extern "C" void kernel_launch(void* const* d_in, const int* in_sizes, int n_in,
                              void* d_out, int out_size, void* d_ws, size_t ws_size,
                              hipStream_t stream) {
    int n = in_sizes[0] / IN_DIM;
    int E = in_sizes[1] / 2;

    const float* x     = (const float*)d_in[0];
    const void*  ei    = d_in[1];
    const float* W_gcn = (const float*)d_in[2];
    const float* b_gcn = (const float*)d_in[3];
    const float* W_gat = (const float*)d_in[4];
    const float* att_s = (const float*)d_in[5];
    const float* att_d = (const float*)d_in[6];
    const float* b_gat = (const float*)d_in[7];
    const float* W_p   = (const float*)d_in[8];
    const float* b_p   = (const float*)d_in[9];
    const float* gamma = (const float*)d_in[10];
    const float* beta  = (const float*)d_in[11];

    int n128 = ((n + 127) / 128) * 128;
    int nch  = (n + 255) / 256;
    int nsb  = (E + 255) / 256;
    int nhb  = nsb < 1024 ? nsb : 1024;
    if (nhb < 1) nhb = 1;

    float* ws = (float*)d_ws;
    size_t off = 0;
    int*   flag    = (int*)(ws + off);  off += 4;
    int*   hist    = (int*)(ws + off);  off += n;
    int*   row_ptr = (int*)(ws + off);  off += n;
    int*   cursor  = (int*)(ws + off);  off += n;
    int*   colv    = (int*)(ws + off);  off += E;
    float* dinv    = ws + off;          off += n;
    float* w_s     = ws + off;          off += HEADS * HID;
    float* w_d     = ws + off;          off += HEADS * HID;
    off = (off + 1) & ~(size_t)1;
    ull*   A       = (ull*)(ws + off);  off += 512;
    off = (off + 3) & ~(size_t)3;
    unsigned short* Wt_post = (unsigned short*)(ws + off); off += 2560 * 8 / 2;
    unsigned short* Wt_xw   = (unsigned short*)(ws + off); off += 1024 * 8 / 2;
    unsigned short* xws = (unsigned short*)(ws + off); off += (size_t)n * HID / 2;
    off = (off + 3) & ~(size_t)3;
    unsigned short* h1b = (unsigned short*)(ws + off); off += (size_t)n128 * HID / 2;
    off = (off + 3) & ~(size_t)3;
    float4* a_sv   = (float4*)(ws + off); off += (size_t)n * 4;
    float4* a_dv   = (float4*)(ws + off); off += (size_t)n * 4;

    hipMemsetAsync(hist, 0, (size_t)n * sizeof(int), stream);
    k_init<<<15 + nhb, 256, 0, stream>>>(ei, E, n, flag, hist, A,
                                         W_gat, W_p, W_gcn, att_s, att_d,
                                         Wt_post, Wt_xw, w_s, w_d);

    k_scan_lb<<<nch, 256, 0, stream>>>(hist, A, row_ptr, cursor, dinv, n);

    k_scatter_xw<<<nsb + (n + 63) / 64, 256, 0, stream>>>(ei, E, flag, cursor,
                                                          colv, x, Wt_xw,
                                                          dinv, xws, n);

    k_gcn<<<(n + 3) / 4, 256, 0, stream>>>(colv, row_ptr, hist, dinv, xws, b_gcn,
                                           w_s, w_d, h1b, a_sv, a_dv, n);

    // FUSED attention (MFMA sparse-agg) + post GEMM + residual/LN
    k_attn_post<<<(n + 15) / 16, 256, 0, stream>>>(colv, row_ptr, hist, a_sv, a_dv,
                                                   h1b, Wt_post, b_p, b_gat,
                                                   gamma, beta, (float*)d_out, n);
}

// Round 9
// 200.293 us; speedup vs baseline: 1.1341x; 1.1341x over previous
//
#include <hip/hip_runtime.h>
#include <math.h>

#define IN_DIM 128
#define HID 64
#define HEADS 4
#define NEG_SLOPE 0.2f
#define LN_EPS 1e-5f
#define APAD 328            // Atile row pitch in bf16 elems (320 + 8 pad)

typedef short bf16x8 __attribute__((ext_vector_type(8)));
typedef float f32x4  __attribute__((ext_vector_type(4)));
typedef unsigned short u16x4 __attribute__((ext_vector_type(4)));
typedef unsigned long long ull;

// ---------- bf16 helpers ----------
__device__ inline unsigned short f2bf(float f) {
    unsigned u = __float_as_uint(f);
    u += 0x7fffu + ((u >> 16) & 1u);     // round-to-nearest-even
    return (unsigned short)(u >> 16);
}
__device__ inline float bf2f(unsigned short s) {
    return __uint_as_float(((unsigned)s) << 16);
}
__device__ inline float leaky(float v) { return v > 0.0f ? v : NEG_SLOPE * v; }

// ---------- fused: weight pre-pack + att fold + flag + A-zero + dst histogram ----------
__global__ __launch_bounds__(256) void k_init(const void* ei, int E, int n,
                           int* flag, int* hist, ull* A,
                           const float* __restrict__ Wg, const float* __restrict__ Wp,
                           const float* __restrict__ Wgcn,
                           const float* __restrict__ att_s, const float* __restrict__ att_d,
                           unsigned short* __restrict__ Wt_post,
                           unsigned short* __restrict__ Wt_xw,
                           float* __restrict__ w_s, float* __restrict__ w_d) {
    int t = threadIdx.x;
    int role = blockIdx.x;
    if (role < 14) {
        int p = role * 256 + t;
        if (p < 2560) {
            int c = p & 63, kg = p >> 6;
            bf16x8 v;
#pragma unroll
            for (int j = 0; j < 8; j++) {
                int k = kg * 8 + j;
                float f;
                if (k < 256) f = 0.25f * Wg[(size_t)(k & 63) * 256 + (k >> 6) * 64 + c];
                else         f = Wp[(size_t)(k - 256) * 64 + c];
                v[j] = (short)f2bf(f);
            }
            *(bf16x8*)(&Wt_post[(size_t)p * 8]) = v;
        } else if (p < 2560 + 1024) {
            int q = p - 2560;
            int c = q & 63, kg = q >> 6;
            bf16x8 v;
#pragma unroll
            for (int j = 0; j < 8; j++)
                v[j] = (short)f2bf(Wgcn[(size_t)(kg * 8 + j) * 64 + c]);
            *(bf16x8*)(&Wt_xw[(size_t)q * 8]) = v;
        }
        return;
    }
    if (role == 14) {
        A[t] = 0ULL;                       // lookback state (nch <= 256)
        __shared__ int s_bad;
        if (t == 0) s_bad = 0;
        __syncthreads();
        int lim = E < 512 ? E : 512;
        int bad = 0;
        for (int k = t; k < lim; k += 256)
            if (((const ull*)ei)[k] >= (ull)n) bad = 1;
        if (bad) s_bad = 1;                // benign race
        __syncthreads();
        if (t == 0) *flag = s_bad ? 0 : 1; // 1 = genuine int64
        int h = t >> 6, k = t & 63;
        float ss = 0.0f, sd = 0.0f;
        for (int c = 0; c < HID; c++) {
            float w = Wg[(size_t)k * (HEADS * HID) + h * HID + c];
            ss += w * att_s[h * HID + c];
            sd += w * att_d[h * HID + c];
        }
        w_s[h * HID + k] = ss;
        w_d[h * HID + k] = sd;
        return;
    }
    __shared__ int s_bad2;
    if (t == 0) s_bad2 = 0;
    __syncthreads();
    int lim = E < 512 ? E : 512;
    int bad = 0;
    for (int k = t; k < lim; k += 256)
        if (((const ull*)ei)[k] >= (ull)n) bad = 1;
    if (bad) s_bad2 = 1;
    __syncthreads();
    int is64 = s_bad2 ? 0 : 1;
    int hb = role - 15;
    int nhb = gridDim.x - 15;
    for (int i = hb * 256 + t; i < E; i += nhb * 256) {
        int d;
        if (is64) d = (int)((const long long*)ei)[E + i];
        else      d = ((const int*)ei)[E + i];
        atomicAdd(&hist[d], 1);
    }
}

// ---------- single-kernel scan: per-chunk scan + wave-parallel decoupled lookback ----------
__global__ __launch_bounds__(256) void k_scan_lb(const int* __restrict__ hist,
                                                 ull* __restrict__ A,
                                                 int* __restrict__ row_ptr,
                                                 int* __restrict__ cursor,
                                                 float* __restrict__ dinv, int n) {
    __shared__ int s[256];
    __shared__ int sbase;
    int t = threadIdx.x, c = blockIdx.x;
    int w = t >> 6, lane = t & 63;
    int i = c * 256 + t;
    int v = (i < n) ? hist[i] : 0;
    s[t] = v;
    __syncthreads();
    for (int off = 1; off < 256; off <<= 1) {
        int xv = (t >= off) ? s[t - off] : 0;
        __syncthreads();
        s[t] += xv;
        __syncthreads();
    }
    int incl = s[t];
    int S = s[255];
    if (t == 0) {
        if (c == 0) { sbase = 0; atomicExch(&A[0], (2ULL << 32) | (unsigned)S); }
        else          atomicExch(&A[c], (1ULL << 32) | (unsigned)S);
    }
    if (c > 0 && w == 0) {
        long long run = 0;
        int p = c - 1;
        for (;;) {
            int idx = p - lane;
            unsigned st, val;
            if (idx >= 0) {
                ull v2 = atomicAdd(&A[idx], 0ULL);
                st = (unsigned)(v2 >> 32); val = (unsigned)v2;
            } else { st = 2u; val = 0u; }
            ull pm = __ballot(st == 2);
            ull zm = __ballot(st == 0);
            int firstP = pm ? (__ffsll((long long)pm) - 1) : 64;
            int firstZ = zm ? (__ffsll((long long)zm) - 1) : 64;
            if (firstZ < firstP) { __builtin_amdgcn_s_sleep(1); continue; }
            unsigned contrib = (lane <= firstP) ? val : 0u;
#pragma unroll
            for (int o = 1; o <= 32; o <<= 1) contrib += __shfl_xor(contrib, o, 64);
            run += contrib;
            if (firstP < 64) break;
            p -= 64;
        }
        if (lane == 0) {
            sbase = (int)run;
            atomicExch(&A[c], (2ULL << 32) | (unsigned)(run + (unsigned)S));
        }
    }
    __syncthreads();
    if (i < n) {
        int excl = sbase + incl - v;
        row_ptr[i] = excl;
        cursor[i] = excl;
        dinv[i] = rsqrtf((float)(v + 1));   // +1 self-loop
    }
}

// ---------- fused: CSR scatter (from raw edge_index) + MFMA x@W_gcn ----------
__global__ __launch_bounds__(256) void k_scatter_xw(const void* ei, int E,
                                                    const int* __restrict__ flag,
                                                    int* __restrict__ cursor,
                                                    int* __restrict__ col,
                                                    const float* __restrict__ x,
                                                    const unsigned short* __restrict__ Wt_g,
                                                    const float* __restrict__ dinv,
                                                    unsigned short* __restrict__ xws, int n) {
    __shared__ unsigned short Wt[16 * 64 * 8];   // 16 KB (used by xw half only)
    int nsb = (E + 255) >> 8;
    if ((int)blockIdx.x < nsb) {
        int i = blockIdx.x * 256 + threadIdx.x;
        if (i >= E) return;
        int is64 = *flag;
        int s, d;
        if (is64) { s = (int)((const long long*)ei)[i]; d = (int)((const long long*)ei)[E + i]; }
        else      { s = ((const int*)ei)[i];            d = ((const int*)ei)[E + i]; }
        int pos = atomicAdd(&cursor[d], 1);
        col[pos] = s;
    } else {
        int bx = blockIdx.x - nsb;
        int t = threadIdx.x;
        for (int idx = t; idx < 1024; idx += 256)
            *(bf16x8*)(&Wt[idx * 8]) = *(const bf16x8*)(&Wt_g[(size_t)idx * 8]);
        __syncthreads();
        int lane = t & 63;
        int li = lane & 15, quad = lane >> 4;
        int w = t >> 6;
        int r0 = bx * 64 + w * 16;
        int rload = r0 + li; if (rload > n - 1) rload = n - 1;
        f32x4 acc[4];
#pragma unroll
        for (int i = 0; i < 4; i++) acc[i] = (f32x4){0.f, 0.f, 0.f, 0.f};
        const float* xp = x + (size_t)rload * IN_DIM + quad * 8;
#pragma unroll
        for (int ks = 0; ks < 4; ks++) {
            float4 p0 = *(const float4*)(xp + ks * 32);
            float4 p1 = *(const float4*)(xp + ks * 32 + 4);
            bf16x8 a;
            a[0] = (short)f2bf(p0.x); a[1] = (short)f2bf(p0.y);
            a[2] = (short)f2bf(p0.z); a[3] = (short)f2bf(p0.w);
            a[4] = (short)f2bf(p1.x); a[5] = (short)f2bf(p1.y);
            a[6] = (short)f2bf(p1.z); a[7] = (short)f2bf(p1.w);
            int kg = ks * 4 + quad;
#pragma unroll
            for (int tt = 0; tt < 4; tt++) {
                bf16x8 bfr = *(const bf16x8*)(&Wt[((kg * 64) + tt * 16 + li) * 8]);
                acc[tt] = __builtin_amdgcn_mfma_f32_16x16x32_bf16(a, bfr, acc[tt], 0, 0, 0);
            }
        }
#pragma unroll
        for (int reg = 0; reg < 4; reg++) {
            int r = r0 + quad * 4 + reg;
            if (r >= n) continue;
            float dv = dinv[r];
#pragma unroll
            for (int tt = 0; tt < 4; tt++)
                xws[(size_t)r * HID + tt * 16 + li] = f2bf(acc[tt][reg] * dv);
        }
    }
}

// ---------- GCN gather: broadcast col loads, 4 gathers in flight ----------
__global__ __launch_bounds__(256) void k_gcn(const int* __restrict__ col,
                                             const int* __restrict__ row_ptr,
                                             const int* __restrict__ hist,
                                             const float* __restrict__ dinv,
                                             const unsigned short* __restrict__ xws,
                                             const float* __restrict__ b,
                                             const float* __restrict__ w_s,
                                             const float* __restrict__ w_d,
                                             unsigned short* __restrict__ h1b,
                                             float4* __restrict__ a_s,
                                             float4* __restrict__ a_d, int n) {
    int t = threadIdx.x;
    int w = t >> 6, lane = t & 63, q = lane >> 4, li = lane & 15;
    int d = blockIdx.x * 4 + w;
    if (d >= n) return;
    int start = row_ptr[d], cnt = hist[d];
    float a0, a1, a2, a3;
    {
        u16x4 sv = *(const u16x4*)(xws + (size_t)d * HID + li * 4);
        float z = (q == 0) ? 1.0f : 0.0f;
        a0 = z * bf2f(sv[0]); a1 = z * bf2f(sv[1]);
        a2 = z * bf2f(sv[2]); a3 = z * bf2f(sv[3]);
    }
    for (int kb = q; kb < cnt; kb += 16) {
        int k1 = kb + 4, k2 = kb + 8, k3 = kb + 12;
        int i1 = k1 < cnt ? k1 : kb;
        int i2 = k2 < cnt ? k2 : kb;
        int i3 = k3 < cnt ? k3 : kb;
        int s0 = col[start + kb];
        int s1 = col[start + i1];
        int s2 = col[start + i2];
        int s3 = col[start + i3];
        u16x4 v0 = *(const u16x4*)(xws + (size_t)s0 * HID + li * 4);
        u16x4 v1 = *(const u16x4*)(xws + (size_t)s1 * HID + li * 4);
        u16x4 v2 = *(const u16x4*)(xws + (size_t)s2 * HID + li * 4);
        u16x4 v3 = *(const u16x4*)(xws + (size_t)s3 * HID + li * 4);
        float g1 = (k1 < cnt) ? 1.0f : 0.0f;
        float g2 = (k2 < cnt) ? 1.0f : 0.0f;
        float g3 = (k3 < cnt) ? 1.0f : 0.0f;
        a0 += (bf2f(v0[0]) + g1 * bf2f(v1[0])) + (g2 * bf2f(v2[0]) + g3 * bf2f(v3[0]));
        a1 += (bf2f(v0[1]) + g1 * bf2f(v1[1])) + (g2 * bf2f(v2[1]) + g3 * bf2f(v3[1]));
        a2 += (bf2f(v0[2]) + g1 * bf2f(v1[2])) + (g2 * bf2f(v2[2]) + g3 * bf2f(v3[2]));
        a3 += (bf2f(v0[3]) + g1 * bf2f(v1[3])) + (g2 * bf2f(v2[3]) + g3 * bf2f(v3[3]));
    }
    a0 += __shfl_xor(a0, 16, 64); a1 += __shfl_xor(a1, 16, 64);
    a2 += __shfl_xor(a2, 16, 64); a3 += __shfl_xor(a3, 16, 64);
    a0 += __shfl_xor(a0, 32, 64); a1 += __shfl_xor(a1, 32, 64);
    a2 += __shfl_xor(a2, 32, 64); a3 += __shfl_xor(a3, 32, 64);
    float dv = dinv[d];
    float4 bv = *(const float4*)(b + li * 4);
    float h0 = fmaxf(a0 * dv + bv.x, 0.0f);
    float h1 = fmaxf(a1 * dv + bv.y, 0.0f);
    float h2 = fmaxf(a2 * dv + bv.z, 0.0f);
    float h3 = fmaxf(a3 * dv + bv.w, 0.0f);
    if (q == 0) {
        u16x4 o;
        o[0] = f2bf(h0); o[1] = f2bf(h1); o[2] = f2bf(h2); o[3] = f2bf(h3);
        *(u16x4*)(h1b + (size_t)d * HID + li * 4) = o;
    }
    float4 u  = *(const float4*)(w_s + q * 64 + li * 4);
    float vs = h0 * u.x + h1 * u.y + h2 * u.z + h3 * u.w;
    float4 u2 = *(const float4*)(w_d + q * 64 + li * 4);
    float vd = h0 * u2.x + h1 * u2.y + h2 * u2.z + h3 * u2.w;
#pragma unroll
    for (int o = 1; o <= 8; o <<= 1) {
        vs += __shfl_xor(vs, o, 64);
        vd += __shfl_xor(vd, o, 64);
    }
    float vs1 = __shfl(vs, 16, 64), vs2 = __shfl(vs, 32, 64), vs3 = __shfl(vs, 48, 64);
    float vd1 = __shfl(vd, 16, 64), vd2 = __shfl(vd, 32, 64), vd3 = __shfl(vd, 48, 64);
    if (lane == 0) {
        a_s[d] = make_float4(vs, vs1, vs2, vs3);
        a_d[d] = make_float4(vd, vd1, vd2, vd3);
    }
}

// ---------- FUSED attention + post-GEMM + residual/LN ----------
// Phase A (quarter-per-dst): quarter q of wave w owns dst rowbase+w*4+q; its 16
// lanes own 4 channels each (full 64-ch row, NO cross-lane reduction). All 4 dsts
// of a wave proceed concurrently; 2-deep edge unroll -> 8 gathers in flight/wave.
// Phase B: 10-slice MFMA [Atile | h1] @ Wt_post. Phase C: LayerNorm. (verified)
__global__ __launch_bounds__(256) void k_attn_post(
        const int* __restrict__ col, const int* __restrict__ row_ptr,
        const int* __restrict__ hist,
        const float4* __restrict__ a_s, const float4* __restrict__ a_d,
        const unsigned short* __restrict__ h1b,
        const unsigned short* __restrict__ Wt_g,
        const float* __restrict__ bp, const float* __restrict__ bg,
        const float* __restrict__ gamma, const float* __restrict__ beta,
        float* __restrict__ out, int n) {
    __shared__ unsigned short Atile[16 * APAD];   // 10.25 KB
    __shared__ float hbuf[16 * 68];               // 4.25 KB
    int t = threadIdx.x;
    int w = t >> 6, lane = t & 63, q = lane >> 4, li = lane & 15;
    int rowbase = blockIdx.x * 16;

    {
        int r = w * 4 + q;            // this quarter's Atile row
        int d = rowbase + r;
        if (d >= n) {
            u16x4 z4 = {0, 0, 0, 0};
#pragma unroll
            for (int h = 0; h < 5; h++)
                *(u16x4*)(&Atile[r * APAD + h * 64 + li * 4]) = z4;
        } else {
            int start = row_ptr[d], cnt = hist[d];
            float4 ad = a_d[d];       // quarter-uniform
            float4 asd = a_s[d];
            u16x4 sv = *(const u16x4*)(h1b + (size_t)d * HID + li * 4);
            // self edge
            float e0 = __expf(leaky(asd.x + ad.x));
            float e1 = __expf(leaky(asd.y + ad.y));
            float e2 = __expf(leaky(asd.z + ad.z));
            float e3 = __expf(leaky(asd.w + ad.w));
            float f0 = bf2f(sv[0]), f1 = bf2f(sv[1]), f2 = bf2f(sv[2]), f3 = bf2f(sv[3]);
            f32x4 A0 = {e0 * f0, e0 * f1, e0 * f2, e0 * f3};   // head0 x my 4 ch
            f32x4 A1 = {e1 * f0, e1 * f1, e1 * f2, e1 * f3};
            f32x4 A2 = {e2 * f0, e2 * f1, e2 * f2, e2 * f3};
            f32x4 A3 = {e3 * f0, e3 * f1, e3 * f2, e3 * f3};
            float l0 = e0, l1 = e1, l2 = e2, l3 = e3;
            for (int kb = 0; kb < cnt; kb += 2) {   // 2 edges in flight per quarter
                int k1 = kb + 1;
                int i1 = k1 < cnt ? k1 : kb;
                int s0 = col[start + kb];
                int s1 = col[start + i1];
                float4 as0 = a_s[s0];
                float4 as1 = a_s[s1];
                u16x4 hv0 = *(const u16x4*)(h1b + (size_t)s0 * HID + li * 4);
                u16x4 hv1 = *(const u16x4*)(h1b + (size_t)s1 * HID + li * 4);
                float g1 = (k1 < cnt) ? 1.0f : 0.0f;
                float w00 = __expf(leaky(as0.x + ad.x));
                float w01 = __expf(leaky(as0.y + ad.y));
                float w02 = __expf(leaky(as0.z + ad.z));
                float w03 = __expf(leaky(as0.w + ad.w));
                float w10 = g1 * __expf(leaky(as1.x + ad.x));
                float w11 = g1 * __expf(leaky(as1.y + ad.y));
                float w12 = g1 * __expf(leaky(as1.z + ad.z));
                float w13 = g1 * __expf(leaky(as1.w + ad.w));
                float g00 = bf2f(hv0[0]), g01 = bf2f(hv0[1]);
                float g02 = bf2f(hv0[2]), g03 = bf2f(hv0[3]);
                float g10 = bf2f(hv1[0]), g11 = bf2f(hv1[1]);
                float g12 = bf2f(hv1[2]), g13 = bf2f(hv1[3]);
                A0[0] += w00 * g00 + w10 * g10; A0[1] += w00 * g01 + w10 * g11;
                A0[2] += w00 * g02 + w10 * g12; A0[3] += w00 * g03 + w10 * g13;
                A1[0] += w01 * g00 + w11 * g10; A1[1] += w01 * g01 + w11 * g11;
                A1[2] += w01 * g02 + w11 * g12; A1[3] += w01 * g03 + w11 * g13;
                A2[0] += w02 * g00 + w12 * g10; A2[1] += w02 * g01 + w12 * g11;
                A2[2] += w02 * g02 + w12 * g12; A2[3] += w02 * g03 + w12 * g13;
                A3[0] += w03 * g00 + w13 * g10; A3[1] += w03 * g01 + w13 * g11;
                A3[2] += w03 * g02 + w13 * g12; A3[3] += w03 * g03 + w13 * g13;
                l0 += w00 + w10; l1 += w01 + w11;
                l2 += w02 + w12; l3 += w03 + w13;
            }
            // direct write: lane covers its 4 channels for all 4 heads + h1 residual
            float inv0 = 1.0f / l0, inv1 = 1.0f / l1, inv2 = 1.0f / l2, inv3 = 1.0f / l3;
            u16x4 o0, o1, o2, o3;
            o0[0] = f2bf(A0[0] * inv0); o0[1] = f2bf(A0[1] * inv0);
            o0[2] = f2bf(A0[2] * inv0); o0[3] = f2bf(A0[3] * inv0);
            o1[0] = f2bf(A1[0] * inv1); o1[1] = f2bf(A1[1] * inv1);
            o1[2] = f2bf(A1[2] * inv1); o1[3] = f2bf(A1[3] * inv1);
            o2[0] = f2bf(A2[0] * inv2); o2[1] = f2bf(A2[1] * inv2);
            o2[2] = f2bf(A2[2] * inv2); o2[3] = f2bf(A2[3] * inv2);
            o3[0] = f2bf(A3[0] * inv3); o3[1] = f2bf(A3[1] * inv3);
            o3[2] = f2bf(A3[2] * inv3); o3[3] = f2bf(A3[3] * inv3);
            *(u16x4*)(&Atile[r * APAD + 0 * 64 + li * 4]) = o0;
            *(u16x4*)(&Atile[r * APAD + 1 * 64 + li * 4]) = o1;
            *(u16x4*)(&Atile[r * APAD + 2 * 64 + li * 4]) = o2;
            *(u16x4*)(&Atile[r * APAD + 3 * 64 + li * 4]) = o3;
            *(u16x4*)(&Atile[r * APAD + 256 + li * 4]) = sv;   // h1 row for ks=8,9 + residual
        }
    }
    __syncthreads();

    // ---- Phase B: MFMA. Wave w -> out cols w*16..+15, rows 0..15. ----
    f32x4 acc_a = {0.f, 0.f, 0.f, 0.f}, acc_h = {0.f, 0.f, 0.f, 0.f};
#pragma unroll
    for (int ks = 0; ks < 10; ks++) {
        int kg = ks * 4 + q;
        bf16x8 a = *(const bf16x8*)(&Atile[li * APAD + ks * 32 + q * 8]);
        bf16x8 bb = *(const bf16x8*)(&Wt_g[(size_t)(kg * 64 + w * 16 + li) * 8]);
        if (ks < 8) acc_a = __builtin_amdgcn_mfma_f32_16x16x32_bf16(a, bb, acc_a, 0, 0, 0);
        else        acc_h = __builtin_amdgcn_mfma_f32_16x16x32_bf16(a, bb, acc_h, 0, 0, 0);
    }
    int cc = w * 16 + li;
    float bgv = bg[cc], bpv = bp[cc];
#pragma unroll
    for (int reg = 0; reg < 4; reg++) {
        int r = q * 4 + reg;
        float h1c = bf2f(Atile[r * APAD + 256 + cc]);
        float h2v = fmaxf(acc_a[reg] + bgv, 0.0f);
        hbuf[r * 68 + cc] = h1c + h2v + acc_h[reg] + bpv;
    }
    __syncthreads();

    // ---- Phase C: LayerNorm (16 threads per row, 4 cols each) ----
    int row = t >> 4, lj = t & 15;
    f32x4 hv4 = *(const f32x4*)(&hbuf[row * 68 + lj * 4]);
    float s1 = (hv4[0] + hv4[1]) + (hv4[2] + hv4[3]);
    float s2 = (hv4[0] * hv4[0] + hv4[1] * hv4[1]) + (hv4[2] * hv4[2] + hv4[3] * hv4[3]);
#pragma unroll
    for (int o = 1; o <= 8; o <<= 1) {
        s1 += __shfl_xor(s1, o, 64);
        s2 += __shfl_xor(s2, o, 64);
    }
    float mu = s1 * (1.0f / 64.0f);
    float var = s2 * (1.0f / 64.0f) - mu * mu;
    float rs = rsqrtf(var + LN_EPS);
    int rg = rowbase + row;
    if (rg < n) {
        float4 g4 = *(const float4*)(gamma + lj * 4);
        float4 b4 = *(const float4*)(beta + lj * 4);
        float4 ov;
        ov.x = (hv4[0] - mu) * rs * g4.x + b4.x;
        ov.y = (hv4[1] - mu) * rs * g4.y + b4.y;
        ov.z = (hv4[2] - mu) * rs * g4.z + b4.z;
        ov.w = (hv4[3] - mu) * rs * g4.w + b4.w;
        *(float4*)(out + (size_t)rg * HID + lj * 4) = ov;
    }
}

extern "C" void kernel_launch(void* const* d_in, const int* in_sizes, int n_in,
                              void* d_out, int out_size, void* d_ws, size_t ws_size,
                              hipStream_t stream) {
    int n = in_sizes[0] / IN_DIM;
    int E = in_sizes[1] / 2;

    const float* x     = (const float*)d_in[0];
    const void*  ei    = d_in[1];
    const float* W_gcn = (const float*)d_in[2];
    const float* b_gcn = (const float*)d_in[3];
    const float* W_gat = (const float*)d_in[4];
    const float* att_s = (const float*)d_in[5];
    const float* att_d = (const float*)d_in[6];
    const float* b_gat = (const float*)d_in[7];
    const float* W_p   = (const float*)d_in[8];
    const float* b_p   = (const float*)d_in[9];
    const float* gamma = (const float*)d_in[10];
    const float* beta  = (const float*)d_in[11];

    int n128 = ((n + 127) / 128) * 128;
    int nch  = (n + 255) / 256;
    int nsb  = (E + 255) / 256;
    int nhb  = nsb < 1024 ? nsb : 1024;
    if (nhb < 1) nhb = 1;

    float* ws = (float*)d_ws;
    size_t off = 0;
    int*   flag    = (int*)(ws + off);  off += 4;
    int*   hist    = (int*)(ws + off);  off += n;
    int*   row_ptr = (int*)(ws + off);  off += n;
    int*   cursor  = (int*)(ws + off);  off += n;
    int*   colv    = (int*)(ws + off);  off += E;
    float* dinv    = ws + off;          off += n;
    float* w_s     = ws + off;          off += HEADS * HID;
    float* w_d     = ws + off;          off += HEADS * HID;
    off = (off + 1) & ~(size_t)1;
    ull*   A       = (ull*)(ws + off);  off += 512;
    off = (off + 3) & ~(size_t)3;
    unsigned short* Wt_post = (unsigned short*)(ws + off); off += 2560 * 8 / 2;
    unsigned short* Wt_xw   = (unsigned short*)(ws + off); off += 1024 * 8 / 2;
    unsigned short* xws = (unsigned short*)(ws + off); off += (size_t)n * HID / 2;
    off = (off + 3) & ~(size_t)3;
    unsigned short* h1b = (unsigned short*)(ws + off); off += (size_t)n128 * HID / 2;
    off = (off + 3) & ~(size_t)3;
    float4* a_sv   = (float4*)(ws + off); off += (size_t)n * 4;
    float4* a_dv   = (float4*)(ws + off); off += (size_t)n * 4;

    hipMemsetAsync(hist, 0, (size_t)n * sizeof(int), stream);
    k_init<<<15 + nhb, 256, 0, stream>>>(ei, E, n, flag, hist, A,
                                         W_gat, W_p, W_gcn, att_s, att_d,
                                         Wt_post, Wt_xw, w_s, w_d);

    k_scan_lb<<<nch, 256, 0, stream>>>(hist, A, row_ptr, cursor, dinv, n);

    k_scatter_xw<<<nsb + (n + 63) / 64, 256, 0, stream>>>(ei, E, flag, cursor,
                                                          colv, x, Wt_xw,
                                                          dinv, xws, n);

    k_gcn<<<(n + 3) / 4, 256, 0, stream>>>(colv, row_ptr, hist, dinv, xws, b_gcn,
                                           w_s, w_d, h1b, a_sv, a_dv, n);

    // FUSED attention (quarter-per-dst, no reductions) + post GEMM + residual/LN
    k_attn_post<<<(n + 15) / 16, 256, 0, stream>>>(colv, row_ptr, hist, a_sv, a_dv,
                                                   h1b, Wt_post, b_p, b_gat,
                                                   gamma, beta, (float*)d_out, n);
}